// Round 1
// baseline (76.626 us; speedup 1.0000x reference)
//
#include <hip/hip_runtime.h>
#include <hip/hip_fp16.h>

#define BIGV 1e9f
#define NPT 256           // N == M == 256
#define NDIAG 511         // anti-diagonals s = 0..510
#define DSTR 64           // ws stride per diagonal (floats)
#define DLROW 52          // max band cells per diagonal (|i-j|<=51 -> <=52)
#define DLSZ (513*DLROW + 64)   // f16 D in LDS, padded for 2-deep prefetch

// band: |i-j| <= 51.  i-window on diagonal s:
__device__ __forceinline__ int imin_of(int s){
    int a = s - 255; if (a < 0) a = 0;            // j = s-i <= 255
    int c = s - 50;  c = (c > 0) ? (c >> 1) : 0;  // ceil((s-51)/2)
    return (a > c) ? a : c;
}
__device__ __forceinline__ int imax_of(int s){
    int a = (s < 255) ? s : 255;
    int c = (s + 51) >> 1;                        // floor((s+51)/2)
    return (a < c) ? a : c;
}

// ---------------- Kernel A: banded distance matrix -> d_ws ----------------
// grid = B*8 blocks: block (b, chunk c) computes diagonals s in [64c, 64c+63]
__global__ __launch_bounds__(256) void ldtw_dist(const float* __restrict__ X,
                                                 const float* __restrict__ Y,
                                                 float* __restrict__ Dws)
{
    __shared__ float4 Xs[96*17];   // rows stride 17 float4 (uniform bank spread)
    __shared__ float4 Ys[96*17];
    __shared__ float nX[96], nY[96];
    const int b  = blockIdx.x >> 3;
    const int c  = blockIdx.x & 7;
    const int s0 = c << 6;
    const int s1 = (s0 + 63 > 510) ? 510 : (s0 + 63);
    const int ilo = imin_of(s0), ihi = imax_of(s1);
    const int jlo = s0 - imax_of(s0), jhi = s1 - imin_of(s1);
    const int nx = ihi - ilo + 1, ny = jhi - jlo + 1;   // each <= 85
    const int t = threadIdx.x;
    const float4* Xb = (const float4*)(X + (size_t)b * NPT * 64);
    const float4* Yb = (const float4*)(Y + (size_t)b * NPT * 64);

    for (int idx = t; idx < nx * 16; idx += 256){
        int r = idx >> 4, k = idx & 15;
        Xs[r*17 + k] = Xb[(ilo + r)*16 + k];
    }
    for (int idx = t; idx < ny * 16; idx += 256){
        int r = idx >> 4, k = idx & 15;
        Ys[r*17 + k] = Yb[(jlo + r)*16 + k];
    }
    __syncthreads();

    for (int r = t; r < nx + ny; r += 256){
        const float4* row = (r < nx) ? (Xs + r*17) : (Ys + (r - nx)*17);
        float acc = 0.f;
        #pragma unroll
        for (int k = 0; k < 16; ++k){
            float4 v = row[k];
            acc += v.x*v.x + v.y*v.y + v.z*v.z + v.w*v.w;
        }
        if (r < nx) nX[r] = acc; else nY[r - nx] = acc;
    }
    __syncthreads();

    for (int slot = t; slot < 64*64; slot += 256){
        const int sd = slot >> 6;
        const int l  = slot & 63;
        const int s  = s0 + sd;
        if (s > 510) continue;
        const int im = imin_of(s);
        const int i  = im + l;
        if (i > imax_of(s)) continue;
        const int j  = s - i;
        const float4* xr = Xs + (i - ilo)*17;
        const float4* yr = Ys + (j - jlo)*17;
        float dot = 0.f;
        #pragma unroll
        for (int k = 0; k < 16; ++k){
            float4 a = xr[k], bb = yr[k];
            dot += a.x*bb.x + a.y*bb.y + a.z*bb.z + a.w*bb.w;
        }
        Dws[((size_t)b*512 + s)*DSTR + l] = nX[i - ilo] + nY[j - jlo] - 2.f*dot;
    }
}

// ---------------- Kernel B: banded DTW DP (one wave per batch) ----------------
__global__ __launch_bounds__(256) void ldtw_dp(const float* __restrict__ Dws,
                                               float* __restrict__ out)
{
    __shared__ __half Dl[DLSZ];
    const int b = blockIdx.x;
    const int t = threadIdx.x;
    // stage D (f32 global -> f16 LDS), all 4 waves
    for (int idx = t; idx < NDIAG*DLROW; idx += 256){
        int s = idx / DLROW;
        int l = idx - s*DLROW;
        Dl[idx] = __float2half(Dws[((size_t)b*512 + s)*DSTR + l]);
    }
    for (int idx = NDIAG*DLROW + t; idx < DLSZ; idx += 256)
        Dl[idx] = __float2half(0.f);
    __syncthreads();
    if (t >= 64) return;          // DP runs on wave 0 only (no further barriers)

    const int l = t;
    // s = 0: only cell (0,0); virtual dp_{-1} is all BIG
    float prev1 = (l == 0) ? __half2float(Dl[0]) : BIGV;
    float prev2 = BIGV;
    int base1 = 0, base2 = 0;
    __half hA = Dl[1*DLROW + l];  // D[s=1]
    __half hB = Dl[2*DLROW + l];  // D[s=2]

    for (int s = 1; s <= 510; ++s){
        __half hN = Dl[(s + 2)*DLROW + l];       // prefetch D[s+2]
        const int im = imin_of(s);
        const int ix = imax_of(s);
        const int d1 = im - base1;               // in {0,1}
        const int d2 = im - base2;               // in {0,1,2}
        const int pu  = l + d1 - 1;              // dp_{s-1}[i-1]  (up)
        const int pl_ = l + d1;                  // dp_{s-1}[i]    (left)
        const int pd  = l + d2 - 1;              // dp_{s-2}[i-1]  (diag)
        float vu = __shfl(prev1, pu  & 63);
        float vl = __shfl(prev1, pl_ & 63);
        float vd = __shfl(prev2, pd  & 63);
        vu = ((unsigned)pu  < 64u) ? vu : BIGV;
        vl = ((unsigned)pl_ < 64u) ? vl : BIGV;
        vd = ((unsigned)pd  < 64u) ? vd : BIGV;
        float m3 = fminf(fminf(vu, vl), vd);
        float cur = (l <= ix - im) ? (m3 + __half2float(hA)) : BIGV;
        prev2 = prev1; base2 = base1;
        prev1 = cur;   base1 = im;
        hA = hB; hB = hN;
    }
    if (l == 0) out[b] = prev1;   // lane 0 holds cell (255,255) on s = 510
}

// ---------------- Fallback (tiny ws): fused, D on the fly ----------------
__device__ __forceinline__ float cell_d(const float4* __restrict__ Xb,
                                        const float4* __restrict__ Yb,
                                        int i, int j)
{
    const float4* xr = Xb + i*16;
    const float4* yr = Yb + j*16;
    float acc = 0.f;
    #pragma unroll
    for (int k = 0; k < 16; ++k){
        float4 a = xr[k], bb = yr[k];
        float dx = a.x-bb.x, dy = a.y-bb.y, dz = a.z-bb.z, dw = a.w-bb.w;
        acc += dx*dx + dy*dy + dz*dz + dw*dw;
    }
    return acc;
}

__global__ __launch_bounds__(64) void ldtw_fused_fb(const float* __restrict__ X,
                                                    const float* __restrict__ Y,
                                                    float* __restrict__ out)
{
    const int b = blockIdx.x;
    const int l = threadIdx.x;
    const float4* Xb = (const float4*)(X + (size_t)b * NPT * 64);
    const float4* Yb = (const float4*)(Y + (size_t)b * NPT * 64);
    float prev1 = (l == 0) ? cell_d(Xb, Yb, 0, 0) : BIGV;
    float prev2 = BIGV;
    int base1 = 0, base2 = 0;
    for (int s = 1; s <= 510; ++s){
        const int im = imin_of(s);
        const int ix = imax_of(s);
        const int i  = im + l;
        const bool act = (i <= ix);
        const int ic = act ? i : ix;
        const int j  = s - ic;
        float Dv = cell_d(Xb, Yb, ic, j);
        const int d1 = im - base1, d2 = im - base2;
        const int pu  = l + d1 - 1;
        const int pl_ = l + d1;
        const int pd  = l + d2 - 1;
        float vu = __shfl(prev1, pu  & 63);
        float vl = __shfl(prev1, pl_ & 63);
        float vd = __shfl(prev2, pd  & 63);
        vu = ((unsigned)pu  < 64u) ? vu : BIGV;
        vl = ((unsigned)pl_ < 64u) ? vl : BIGV;
        vd = ((unsigned)pd  < 64u) ? vd : BIGV;
        float m3 = fminf(fminf(vu, vl), vd);
        float cur = act ? (m3 + Dv) : BIGV;
        prev2 = prev1; base2 = base1;
        prev1 = cur;   base1 = im;
    }
    if (l == 0) out[b] = prev1;
}

extern "C" void kernel_launch(void* const* d_in, const int* in_sizes, int n_in,
                              void* d_out, int out_size, void* d_ws, size_t ws_size,
                              hipStream_t stream)
{
    const float* X = (const float*)d_in[0];
    const float* Y = (const float*)d_in[1];
    float* out = (float*)d_out;
    const int Bn = in_sizes[0] / (NPT * 64);     // = 16
    const size_t need = (size_t)Bn * 512 * DSTR * sizeof(float);
    if (ws_size >= need){
        float* Dws = (float*)d_ws;
        hipLaunchKernelGGL(ldtw_dist, dim3(Bn * 8), dim3(256), 0, stream, X, Y, Dws);
        hipLaunchKernelGGL(ldtw_dp,   dim3(Bn),     dim3(256), 0, stream, Dws, out);
    } else {
        hipLaunchKernelGGL(ldtw_fused_fb, dim3(Bn), dim3(64), 0, stream, X, Y, out);
    }
}

// Round 2
// 62.706 us; speedup vs baseline: 1.2220x; 1.2220x over previous
//
#include <hip/hip_runtime.h>
#include <hip/hip_fp16.h>

#define BIGV 1e9f
#define NPT 256            // N == M == 256
#define DROWS 52           // band width max (|i-j|<=51 -> <=52 cells/diag)
#define DPITCH 520         // f16 per LDS row (512 + 8 pad -> 16B aligned, bank spread)

typedef _Float16 half8  __attribute__((ext_vector_type(8)));
typedef _Float16 half2v __attribute__((ext_vector_type(2)));

// band: |i-j| <= 51.  i-window on diagonal s:
__device__ __forceinline__ int imin_of(int s){
    int a = s - 255; if (a < 0) a = 0;            // j = s-i <= 255
    int c = s - 50;  c = (c > 0) ? (c >> 1) : 0;  // ceil((s-51)/2)
    return (a > c) ? a : c;
}
__device__ __forceinline__ int imax_of(int s){
    int a = (s < 255) ? s : 255;
    int c = (s + 51) >> 1;                        // floor((s+51)/2)
    return (a < c) ? a : c;
}

// wave-wide shift by 1 with BIG fill, ~2cy VALU (no LDS): lane l <- x[l-1]
__device__ __forceinline__ float dpp_shr1(float x){
    return __int_as_float(__builtin_amdgcn_update_dpp(
        __float_as_int(BIGV), __float_as_int(x), 0x138 /*WAVE_SHR1*/, 0xF, 0xF, false));
}
// lane l <- x[l+1]
__device__ __forceinline__ float dpp_shl1(float x){
    return __int_as_float(__builtin_amdgcn_update_dpp(
        __float_as_int(BIGV), __float_as_int(x), 0x130 /*WAVE_SHL1*/, 0xF, 0xF, false));
}

// ---------------- Kernel A: banded distance matrix -> d_ws (transposed) ----------
// grid = B*8 blocks: block (b, chunk c) computes diagonals s in [64c, 64c+63]
// Dt layout: Dt[b][l][s], row-major, 64 rows x 512 cols of f32 per batch.
__global__ __launch_bounds__(256) void ldtw_dist(const float* __restrict__ X,
                                                 const float* __restrict__ Y,
                                                 float* __restrict__ Dt)
{
    __shared__ float4 Xs[96*17];   // rows stride 17 float4
    __shared__ float4 Ys[96*17];
    __shared__ float nX[96], nY[96];
    const int b  = blockIdx.x >> 3;
    const int c  = blockIdx.x & 7;
    const int s0 = c << 6;
    const int s1 = (s0 + 63 > 510) ? 510 : (s0 + 63);
    const int ilo = imin_of(s0), ihi = imax_of(s1);
    const int jlo = s0 - imax_of(s0), jhi = s1 - imin_of(s1);
    const int nx = ihi - ilo + 1, ny = jhi - jlo + 1;   // each <= 96
    const int t = threadIdx.x;
    const float4* Xb = (const float4*)(X + (size_t)b * NPT * 64);
    const float4* Yb = (const float4*)(Y + (size_t)b * NPT * 64);

    for (int idx = t; idx < nx * 16; idx += 256){
        int r = idx >> 4, k = idx & 15;
        Xs[r*17 + k] = Xb[(ilo + r)*16 + k];
    }
    for (int idx = t; idx < ny * 16; idx += 256){
        int r = idx >> 4, k = idx & 15;
        Ys[r*17 + k] = Yb[(jlo + r)*16 + k];
    }
    __syncthreads();

    for (int r = t; r < nx + ny; r += 256){
        const float4* row = (r < nx) ? (Xs + r*17) : (Ys + (r - nx)*17);
        float acc = 0.f;
        #pragma unroll
        for (int k = 0; k < 16; ++k){
            float4 v = row[k];
            acc += v.x*v.x + v.y*v.y + v.z*v.z + v.w*v.w;
        }
        if (r < nx) nX[r] = acc; else nY[r - nx] = acc;
    }
    __syncthreads();

    // l-major slots: a wave covers 64 consecutive s at fixed l -> coalesced Dt writes
    for (int slot = t; slot < 64*64; slot += 256){
        const int l  = slot >> 6;
        const int sd = slot & 63;
        const int s  = s0 + sd;
        if (s > 510 || l >= DROWS) continue;
        const int im = imin_of(s);
        const int i  = im + l;
        if (i > imax_of(s)) continue;
        const int j  = s - i;
        const float4* xr = Xs + (i - ilo)*17;
        const float4* yr = Ys + (j - jlo)*17;
        float dot = 0.f;
        #pragma unroll
        for (int k = 0; k < 16; ++k){
            float4 a = xr[k], bb = yr[k];
            dot += a.x*bb.x + a.y*bb.y + a.z*bb.z + a.w*bb.w;
        }
        Dt[(((size_t)b*64 + l) << 9) + s] = nX[i - ilo] + nY[j - jlo] - 2.f*dot;
    }
}

// ---------------- Kernel B: banded DTW DP (one wave per batch) --------------------
__global__ __launch_bounds__(256) void ldtw_dp(const float* __restrict__ Dt,
                                               float* __restrict__ out)
{
    __shared__ _Float16 Dl[DROWS * DPITCH];     // 54,080 B, transposed: Dl[l][s]
    const int b = blockIdx.x;
    const int t = threadIdx.x;

    // stage: coalesced float2 global reads -> packed f16 LDS writes (conflict-free)
    const float2* src = (const float2*)Dt + (size_t)b * 16384;   // b*64*256
    for (int idx = t; idx < DROWS * 256; idx += 256){
        int row = idx >> 8;
        int sp  = idx & 255;
        float2 v = src[(row << 8) + sp];
        half2v h; h.x = (_Float16)v.x; h.y = (_Float16)v.y;
        *(half2v*)(Dl + row*DPITCH + 2*sp) = h;
    }
    __syncthreads();
    if (t >= 64) return;          // DP on wave 0 only; all 64 lanes stay active

    const int l = t;
    const _Float16* rowp = Dl + (l < DROWS ? l : DROWS-1) * DPITCH;

    half8 gc0 = *(const half8*)(rowp);        // D[s=0..7]
    half8 gc1 = *(const half8*)(rowp + 8);    // D[s=8..15]

    float prev2 = BIGV;
    float prev1 = (l == 0) ? (float)gc0[0] : BIGV;   // s = 0: only cell (0,0)
    int base1 = 0, base2 = 0;
    int s = 1;

#define LSTEP(DV) { \
    const int im_ = imin_of(s), ix_ = imax_of(s); \
    const int d1_ = im_ - base1, d2_ = im_ - base2; \
    float sr1 = dpp_shr1(prev1), sl1 = dpp_shl1(prev1); \
    float sr2 = dpp_shr1(prev2), sl2 = dpp_shl1(prev2); \
    float mA = fminf(sr1, prev1); \
    float mB = fminf(prev1, sl1); \
    float m1 = d1_ ? mB : mA; \
    float vd = (d2_ == 0) ? sr2 : ((d2_ == 2) ? sl2 : prev2); \
    float m3 = fminf(m1, vd); \
    float cur = (l <= ix_ - im_) ? (m3 + (DV)) : BIGV; \
    prev2 = prev1; base2 = base1; \
    prev1 = cur;   base1 = im_; \
    ++s; }

    #pragma unroll
    for (int r = 1; r < 8; ++r) LSTEP((float)gc0[r]);          // s = 1..7

    for (int m = 1; m <= 62; ++m){                             // s = 8..503
        half8 gn = *(const half8*)(rowp + (m + 1) * 8);        // prefetch next group
        #pragma unroll
        for (int r = 0; r < 8; ++r) LSTEP((float)gc1[r]);
        gc1 = gn;
    }

    #pragma unroll
    for (int r = 0; r < 7; ++r) LSTEP((float)gc1[r]);          // s = 504..510
#undef LSTEP

    if (l == 0) out[b] = prev1;   // lane 0 holds cell (255,255) at s = 510
}

// ---------------- Fallback (tiny ws): fused, D on the fly ----------------
__device__ __forceinline__ float cell_d(const float4* __restrict__ Xb,
                                        const float4* __restrict__ Yb,
                                        int i, int j)
{
    const float4* xr = Xb + i*16;
    const float4* yr = Yb + j*16;
    float acc = 0.f;
    #pragma unroll
    for (int k = 0; k < 16; ++k){
        float4 a = xr[k], bb = yr[k];
        float dx = a.x-bb.x, dy = a.y-bb.y, dz = a.z-bb.z, dw = a.w-bb.w;
        acc += dx*dx + dy*dy + dz*dz + dw*dw;
    }
    return acc;
}

__global__ __launch_bounds__(64) void ldtw_fused_fb(const float* __restrict__ X,
                                                    const float* __restrict__ Y,
                                                    float* __restrict__ out)
{
    const int b = blockIdx.x;
    const int l = threadIdx.x;
    const float4* Xb = (const float4*)(X + (size_t)b * NPT * 64);
    const float4* Yb = (const float4*)(Y + (size_t)b * NPT * 64);
    float prev1 = (l == 0) ? cell_d(Xb, Yb, 0, 0) : BIGV;
    float prev2 = BIGV;
    int base1 = 0, base2 = 0;
    for (int s = 1; s <= 510; ++s){
        const int im = imin_of(s);
        const int ix = imax_of(s);
        const int i  = im + l;
        const bool act = (i <= ix);
        const int ic = act ? i : ix;
        const int j  = s - ic;
        float Dv = cell_d(Xb, Yb, ic, j);
        const int d1 = im - base1, d2 = im - base2;
        float sr1 = dpp_shr1(prev1), sl1 = dpp_shl1(prev1);
        float sr2 = dpp_shr1(prev2), sl2 = dpp_shl1(prev2);
        float m1 = d1 ? fminf(prev1, sl1) : fminf(sr1, prev1);
        float vd = (d2 == 0) ? sr2 : ((d2 == 2) ? sl2 : prev2);
        float m3 = fminf(m1, vd);
        float cur = act ? (m3 + Dv) : BIGV;
        prev2 = prev1; base2 = base1;
        prev1 = cur;   base1 = im;
    }
    if (l == 0) out[b] = prev1;
}

extern "C" void kernel_launch(void* const* d_in, const int* in_sizes, int n_in,
                              void* d_out, int out_size, void* d_ws, size_t ws_size,
                              hipStream_t stream)
{
    const float* X = (const float*)d_in[0];
    const float* Y = (const float*)d_in[1];
    float* out = (float*)d_out;
    const int Bn = in_sizes[0] / (NPT * 64);     // = 16
    const size_t need = (size_t)Bn * 64 * 512 * sizeof(float);
    if (ws_size >= need){
        float* Dt = (float*)d_ws;
        hipLaunchKernelGGL(ldtw_dist, dim3(Bn * 8), dim3(256), 0, stream, X, Y, Dt);
        hipLaunchKernelGGL(ldtw_dp,   dim3(Bn),     dim3(256), 0, stream, Dt, out);
    } else {
        hipLaunchKernelGGL(ldtw_fused_fb, dim3(Bn), dim3(64), 0, stream, X, Y, out);
    }
}

// Round 3
// 43.373 us; speedup vs baseline: 1.7667x; 1.4457x over previous
//
#include <hip/hip_runtime.h>

#define BIGV 1e9f
#define NPT 256            // N == M == 256

// band: |i-j| <= 51.  i-window on diagonal s:
__device__ __forceinline__ int imin_of(int s){
    int a = s - 255; if (a < 0) a = 0;            // j = s-i <= 255
    int c = s - 50;  c = (c > 0) ? (c >> 1) : 0;  // ceil((s-51)/2)
    return (a > c) ? a : c;
}
__device__ __forceinline__ int imax_of(int s){
    int a = (s < 255) ? s : 255;
    int c = (s + 51) >> 1;                        // floor((s+51)/2)
    return (a < c) ? a : c;
}

// wave-wide shift by 1 with BIG fill (no LDS): lane l <- x[l-1]
__device__ __forceinline__ float dpp_shr1(float x){
    return __int_as_float(__builtin_amdgcn_update_dpp(
        __float_as_int(BIGV), __float_as_int(x), 0x138 /*WAVE_SHR1*/, 0xF, 0xF, false));
}
__device__ __forceinline__ float dpp_shl1(float x){
    return __int_as_float(__builtin_amdgcn_update_dpp(
        __float_as_int(BIGV), __float_as_int(x), 0x130 /*WAVE_SHL1*/, 0xF, 0xF, false));
}

__device__ __forceinline__ unsigned bf16rne(float f){
    unsigned u = __float_as_uint(f);
    u += 0x7FFFu + ((u >> 16) & 1u);
    return u >> 16;
}

// ---------------- Kernel A: banded distances -> full bf16 rows in d_ws -----------
// Df layout: u32-pairs, row (b*512 + s) has 128 u32 = 256 bf16 (i = 0..255),
// BIG outside the band. grid = B*8, block (b,c) owns s in [64c, 64c+63].
__global__ __launch_bounds__(256) void ldtw_dist(const float* __restrict__ X,
                                                 const float* __restrict__ Y,
                                                 unsigned* __restrict__ Df)
{
    __shared__ float4 Xs[96*17];
    __shared__ float4 Ys[96*17];
    __shared__ float nX[96], nY[96];
    __shared__ float Band[64*65];   // pitch 65 -> 2-way-max bank aliasing
    const int b  = blockIdx.x >> 3;
    const int c  = blockIdx.x & 7;
    const int s0 = c << 6;
    const int s1 = (s0 + 63 > 510) ? 510 : (s0 + 63);
    const int ilo = imin_of(s0), ihi = imax_of(s1);
    const int jlo = s0 - imax_of(s0), jhi = s1 - imin_of(s1);
    const int nx = ihi - ilo + 1, ny = jhi - jlo + 1;   // each <= 96
    const int t = threadIdx.x;
    const float4* Xb = (const float4*)(X + (size_t)b * NPT * 64);
    const float4* Yb = (const float4*)(Y + (size_t)b * NPT * 64);

    for (int idx = t; idx < nx * 16; idx += 256){
        int r = idx >> 4, k = idx & 15;
        Xs[r*17 + k] = Xb[(ilo + r)*16 + k];
    }
    for (int idx = t; idx < ny * 16; idx += 256){
        int r = idx >> 4, k = idx & 15;
        Ys[r*17 + k] = Yb[(jlo + r)*16 + k];
    }
    __syncthreads();

    for (int r = t; r < nx + ny; r += 256){
        const float4* row = (r < nx) ? (Xs + r*17) : (Ys + (r - nx)*17);
        float acc = 0.f;
        #pragma unroll
        for (int k = 0; k < 16; ++k){
            float4 v = row[k];
            acc += v.x*v.x + v.y*v.y + v.z*v.z + v.w*v.w;
        }
        if (r < nx) nX[r] = acc; else nY[r - nx] = acc;
    }
    __syncthreads();

    // phase 1: band dot-products into LDS
    for (int slot = t; slot < 64*64; slot += 256){
        const int l  = slot >> 6;
        const int sd = slot & 63;
        const int s  = s0 + sd;
        if (s > 510) continue;
        const int im = imin_of(s);
        const int i  = im + l;
        if (i > imax_of(s)) continue;
        const int j  = s - i;
        const float4* xr = Xs + (i - ilo)*17;
        const float4* yr = Ys + (j - jlo)*17;
        float dot = 0.f;
        #pragma unroll
        for (int k = 0; k < 16; ++k){
            float4 a = xr[k], bb = yr[k];
            dot += a.x*bb.x + a.y*bb.y + a.z*bb.z + a.w*bb.w;
        }
        Band[sd*65 + l] = nX[i - ilo] + nY[j - jlo] - 2.f*dot;
    }
    __syncthreads();

    // phase 2: emit full 256-wide bf16 rows (BIG outside band), coalesced u32 writes
    const size_t rowbase = (size_t)(b * 512 + s0) << 7;   // u32 units, 128 per row
    for (int slot = t; slot < 64*128; slot += 256){
        const int sd = slot >> 7, q = slot & 127;
        const int s  = s0 + sd;
        const int im = imin_of(s), ix = imax_of(s);
        const int i0 = q*2, i1 = q*2 + 1;
        float f0 = BIGV, f1 = BIGV;
        if (s <= 510){
            if (i0 >= im && i0 <= ix) f0 = Band[sd*65 + (i0 - im)];
            if (i1 >= im && i1 <= ix) f1 = Band[sd*65 + (i1 - im)];
        }
        Df[rowbase + ((size_t)sd << 7) + q] = bf16rne(f0) | (bf16rne(f1) << 16);
    }
}

// ---------------- Kernel B: absolute-i DP, 4 cells/lane, 1 wave/batch ------------
__global__ __launch_bounds__(64) void ldtw_dp(const unsigned* __restrict__ Df,
                                              float* __restrict__ out)
{
    const int b = blockIdx.x;
    const int L = threadIdx.x;                         // 0..63, cells i = 4L..4L+3
    const uint2* base = (const uint2*)Df + ((size_t)b << 15) + L;  // row stride 64 uint2

    float p0, p1, p2, p3, q0, q1, q2, q3;
    // s = 0: dp[0][0] = D(0,0), else BIG
    float d00 = __uint_as_float(Df[(size_t)b << 16] << 16);
    p0 = (L == 0) ? d00 : BIGV; p1 = BIGV; p2 = BIGV; p3 = BIGV;
    q0 = BIGV; q1 = BIGV; q2 = BIGV; q3 = BIGV;

#define LOADG(Bk, g) { const uint2* rp_ = base + (size_t)((g)*8 + 1) * 64; \
    Bk##0 = rp_[0];   Bk##1 = rp_[64];  Bk##2 = rp_[128]; Bk##3 = rp_[192]; \
    Bk##4 = rp_[256]; Bk##5 = rp_[320]; Bk##6 = rp_[384]; Bk##7 = rp_[448]; }

#define UNPACK(w, da, db, dc, dd) \
    float da = __uint_as_float((w).x << 16); \
    float db = __uint_as_float((w).x & 0xFFFF0000u); \
    float dc = __uint_as_float((w).y << 16); \
    float dd = __uint_as_float((w).y & 0xFFFF0000u);

    // prev1 = p, prev2 = q -> new into q (q becomes prev1)
#define STEP_PQ(w) { UNPACK(w, da, db, dc, dd) \
    float s1_ = dpp_shr1(p3), s2_ = dpp_shr1(q3); \
    float n0 = fminf(fminf(s1_, p0), s2_) + da; \
    float n1 = fminf(fminf(p0, p1), q0) + db; \
    float n2 = fminf(fminf(p1, p2), q1) + dc; \
    float n3 = fminf(fminf(p2, p3), q2) + dd; \
    q0 = n0; q1 = n1; q2 = n2; q3 = n3; }
#define STEP_QP(w) { UNPACK(w, da, db, dc, dd) \
    float s1_ = dpp_shr1(q3), s2_ = dpp_shr1(p3); \
    float n0 = fminf(fminf(s1_, q0), s2_) + da; \
    float n1 = fminf(fminf(q0, q1), p0) + db; \
    float n2 = fminf(fminf(q1, q2), p1) + dc; \
    float n3 = fminf(fminf(q2, q3), p2) + dd; \
    p0 = n0; p1 = n1; p2 = n2; p3 = n3; }

#define GROUP8(Bk) \
    STEP_PQ(Bk##0) STEP_QP(Bk##1) STEP_PQ(Bk##2) STEP_QP(Bk##3) \
    STEP_PQ(Bk##4) STEP_QP(Bk##5) STEP_PQ(Bk##6) STEP_QP(Bk##7)

    uint2 A0,A1,A2,A3,A4,A5,A6,A7;
    uint2 B0,B1,B2,B3,B4,B5,B6,B7;
    LOADG(A, 0)                       // s = 1..8
    LOADG(B, 1)                       // s = 9..16
    for (int m = 0; m < 62; m += 2){  // consume groups 0..61 (s = 1..496)
        GROUP8(A) LOADG(A, m + 2)
        GROUP8(B) LOADG(B, m + 3)
    }
    GROUP8(A)                         // group 62: s = 497..504
    STEP_PQ(B0) STEP_QP(B1) STEP_PQ(B2) STEP_QP(B3) STEP_PQ(B4) STEP_QP(B5)  // 505..510

    if (L == 63) out[b] = p3;         // dp[510][255]
#undef LOADG
#undef UNPACK
#undef STEP_PQ
#undef STEP_QP
#undef GROUP8
}

// ---------------- Fallback (tiny ws): fused, D on the fly ----------------
__device__ __forceinline__ float cell_d(const float4* __restrict__ Xb,
                                        const float4* __restrict__ Yb,
                                        int i, int j)
{
    const float4* xr = Xb + i*16;
    const float4* yr = Yb + j*16;
    float acc = 0.f;
    #pragma unroll
    for (int k = 0; k < 16; ++k){
        float4 a = xr[k], bb = yr[k];
        float dx = a.x-bb.x, dy = a.y-bb.y, dz = a.z-bb.z, dw = a.w-bb.w;
        acc += dx*dx + dy*dy + dz*dz + dw*dw;
    }
    return acc;
}

__global__ __launch_bounds__(64) void ldtw_fused_fb(const float* __restrict__ X,
                                                    const float* __restrict__ Y,
                                                    float* __restrict__ out)
{
    const int b = blockIdx.x;
    const int l = threadIdx.x;
    const float4* Xb = (const float4*)(X + (size_t)b * NPT * 64);
    const float4* Yb = (const float4*)(Y + (size_t)b * NPT * 64);
    float prev1 = (l == 0) ? cell_d(Xb, Yb, 0, 0) : BIGV;
    float prev2 = BIGV;
    int base1 = 0, base2 = 0;
    for (int s = 1; s <= 510; ++s){
        const int im = imin_of(s);
        const int ix = imax_of(s);
        const int i  = im + l;
        const bool act = (i <= ix);
        const int ic = act ? i : ix;
        const int j  = s - ic;
        float Dv = cell_d(Xb, Yb, ic, j);
        const int d1 = im - base1, d2 = im - base2;
        float sr1 = dpp_shr1(prev1), sl1 = dpp_shl1(prev1);
        float sr2 = dpp_shr1(prev2), sl2 = dpp_shl1(prev2);
        float m1 = d1 ? fminf(prev1, sl1) : fminf(sr1, prev1);
        float vd = (d2 == 0) ? sr2 : ((d2 == 2) ? sl2 : prev2);
        float m3 = fminf(m1, vd);
        float cur = act ? (m3 + Dv) : BIGV;
        prev2 = prev1; base2 = base1;
        prev1 = cur;   base1 = im;
    }
    if (l == 0) out[b] = prev1;
}

extern "C" void kernel_launch(void* const* d_in, const int* in_sizes, int n_in,
                              void* d_out, int out_size, void* d_ws, size_t ws_size,
                              hipStream_t stream)
{
    const float* X = (const float*)d_in[0];
    const float* Y = (const float*)d_in[1];
    float* out = (float*)d_out;
    const int Bn = in_sizes[0] / (NPT * 64);     // = 16
    // Df: Bn * 512 rows * 256 bf16 = Bn * 256 KiB; + slack for the group-63 over-read
    const size_t need = (size_t)Bn * 512 * 256 * 2 + 4096;
    if (ws_size >= need){
        unsigned* Df = (unsigned*)d_ws;
        hipLaunchKernelGGL(ldtw_dist, dim3(Bn * 8), dim3(256), 0, stream, X, Y, Df);
        hipLaunchKernelGGL(ldtw_dp,   dim3(Bn),     dim3(64),  0, stream, Df, out);
    } else {
        hipLaunchKernelGGL(ldtw_fused_fb, dim3(Bn), dim3(64), 0, stream, X, Y, out);
    }
}

// Round 5
// 37.827 us; speedup vs baseline: 2.0257x; 1.1466x over previous
//
#include <hip/hip_runtime.h>

#define BIGV 1e9f
#define NPT 256            // N == M == 256

// band: |i-j| <= 51.  i-window on diagonal s:
__device__ __forceinline__ int imin_of(int s){
    int a = s - 255; if (a < 0) a = 0;            // j = s-i <= 255
    int c = s - 50;  c = (c > 0) ? (c >> 1) : 0;  // ceil((s-51)/2)
    return (a > c) ? a : c;
}
__device__ __forceinline__ int imax_of(int s){
    int a = (s < 255) ? s : 255;
    int c = (s + 51) >> 1;                        // floor((s+51)/2)
    return (a < c) ? a : c;
}

// wave-wide shift by 1 with BIG fill (no LDS): lane l <- x[l-1]
__device__ __forceinline__ float dpp_shr1(float x){
    return __int_as_float(__builtin_amdgcn_update_dpp(
        __float_as_int(BIGV), __float_as_int(x), 0x138 /*WAVE_SHR1*/, 0xF, 0xF, false));
}
__device__ __forceinline__ float dpp_shl1(float x){
    return __int_as_float(__builtin_amdgcn_update_dpp(
        __float_as_int(BIGV), __float_as_int(x), 0x130 /*WAVE_SHL1*/, 0xF, 0xF, false));
}

__device__ __forceinline__ float min3f(float a, float b, float c){
    float r;
    asm("v_min3_f32 %0, %1, %2, %3" : "=v"(r) : "v"(a), "v"(b), "v"(c));
    return r;
}

// ---------------- Kernel A: banded distances -> full f32 rows in d_ws ------------
// Df layout: f32, row (b*512 + s) has 256 floats (i = 0..255), BIG outside band.
// Row s = 511 is written all-BIG. grid = B*8, block (b,c) owns s in [64c, 64c+63].
__global__ __launch_bounds__(256) void ldtw_dist(const float* __restrict__ X,
                                                 const float* __restrict__ Y,
                                                 float* __restrict__ Df)
{
    __shared__ float4 Xs[96*17];
    __shared__ float4 Ys[96*17];
    __shared__ float nX[96], nY[96];
    __shared__ float Band[64*65];   // pitch 65
    const int b  = blockIdx.x >> 3;
    const int c  = blockIdx.x & 7;
    const int s0 = c << 6;
    const int s1 = (s0 + 63 > 510) ? 510 : (s0 + 63);
    const int ilo = imin_of(s0), ihi = imax_of(s1);
    const int jlo = s0 - imax_of(s0), jhi = s1 - imin_of(s1);
    const int nx = ihi - ilo + 1, ny = jhi - jlo + 1;   // each <= 96
    const int t = threadIdx.x;
    const float4* Xb = (const float4*)(X + (size_t)b * NPT * 64);
    const float4* Yb = (const float4*)(Y + (size_t)b * NPT * 64);

    for (int idx = t; idx < nx * 16; idx += 256){
        int r = idx >> 4, k = idx & 15;
        Xs[r*17 + k] = Xb[(ilo + r)*16 + k];
    }
    for (int idx = t; idx < ny * 16; idx += 256){
        int r = idx >> 4, k = idx & 15;
        Ys[r*17 + k] = Yb[(jlo + r)*16 + k];
    }
    __syncthreads();

    for (int r = t; r < nx + ny; r += 256){
        const float4* row = (r < nx) ? (Xs + r*17) : (Ys + (r - nx)*17);
        float acc = 0.f;
        #pragma unroll
        for (int k = 0; k < 16; ++k){
            float4 v = row[k];
            acc += v.x*v.x + v.y*v.y + v.z*v.z + v.w*v.w;
        }
        if (r < nx) nX[r] = acc; else nY[r - nx] = acc;
    }
    __syncthreads();

    // phase 1: band dot-products into LDS
    for (int slot = t; slot < 64*64; slot += 256){
        const int l  = slot >> 6;
        const int sd = slot & 63;
        const int s  = s0 + sd;
        if (s > 510) continue;
        const int im = imin_of(s);
        const int i  = im + l;
        if (i > imax_of(s)) continue;
        const int j  = s - i;
        const float4* xr = Xs + (i - ilo)*17;
        const float4* yr = Ys + (j - jlo)*17;
        float dot = 0.f;
        #pragma unroll
        for (int k = 0; k < 16; ++k){
            float4 a = xr[k], bb = yr[k];
            dot += a.x*bb.x + a.y*bb.y + a.z*bb.z + a.w*bb.w;
        }
        Band[sd*65 + l] = nX[i - ilo] + nY[j - jlo] - 2.f*dot;
    }
    __syncthreads();

    // phase 2: emit full 256-wide f32 rows (BIG outside band), coalesced float4
    float4* Df4 = (float4*)Df;
    const size_t rowbase4 = ((size_t)(b * 512 + s0)) << 6;   // float4 units, 64/row
    for (int slot = t; slot < 64*64; slot += 256){
        const int sd = slot >> 6, q = slot & 63;
        const int s  = s0 + sd;
        float4 v = make_float4(BIGV, BIGV, BIGV, BIGV);
        if (s <= 510){
            const int im = imin_of(s), ix = imax_of(s);
            const int i0 = q << 2;
            if (i0 + 0 >= im && i0 + 0 <= ix) v.x = Band[sd*65 + (i0 + 0 - im)];
            if (i0 + 1 >= im && i0 + 1 <= ix) v.y = Band[sd*65 + (i0 + 1 - im)];
            if (i0 + 2 >= im && i0 + 2 <= ix) v.z = Band[sd*65 + (i0 + 2 - im)];
            if (i0 + 3 >= im && i0 + 3 <= ix) v.w = Band[sd*65 + (i0 + 3 - im)];
        }
        Df4[rowbase4 + ((size_t)sd << 6) + q] = v;
    }
}

// ---------------- Kernel B: absolute-i DP, 4 cells/lane, 1 wave/batch ------------
// f32 D stream, v_min3, 4-deep group prefetch.
__global__ __launch_bounds__(64) void ldtw_dp(const float* __restrict__ Df,
                                              float* __restrict__ out)
{
    const int b = blockIdx.x;
    const int L = threadIdx.x;                        // cells i = 4L..4L+3
    const float4* base = (const float4*)Df + ((size_t)b << 15) + L;  // row stride 64

    float p0, p1, p2, p3, q0, q1, q2, q3;
    float d00 = Df[(size_t)b << 17];                  // D(0,0)
    p0 = (L == 0) ? d00 : BIGV; p1 = BIGV; p2 = BIGV; p3 = BIGV;
    q0 = BIGV; q1 = BIGV; q2 = BIGV; q3 = BIGV;

    // group g covers s = 8g+1 .. 8g+8; two bases keep imm offsets within 4KB
#define LOADG(Bk, g) { \
    const float4* r0_ = base + (size_t)(((g) << 3) + 1) * 64; \
    const float4* r1_ = r0_ + 256; \
    Bk##0 = r0_[0];   Bk##1 = r0_[64];  Bk##2 = r0_[128]; Bk##3 = r0_[192]; \
    Bk##4 = r1_[0];   Bk##5 = r1_[64];  Bk##6 = r1_[128]; Bk##7 = r1_[192]; }

    // prev1 = p, prev2 = q -> new into q (q becomes prev1)
#define STEP_PQ(V) { \
    float s1_ = dpp_shr1(p3), s2_ = dpp_shr1(q3); \
    float n0 = min3f(s1_, p0, s2_) + (V).x; \
    float n1 = min3f(p0, p1, q0) + (V).y; \
    float n2 = min3f(p1, p2, q1) + (V).z; \
    float n3 = min3f(p2, p3, q2) + (V).w; \
    q0 = n0; q1 = n1; q2 = n2; q3 = n3; }
#define STEP_QP(V) { \
    float s1_ = dpp_shr1(q3), s2_ = dpp_shr1(p3); \
    float n0 = min3f(s1_, q0, s2_) + (V).x; \
    float n1 = min3f(q0, q1, p0) + (V).y; \
    float n2 = min3f(q1, q2, p1) + (V).z; \
    float n3 = min3f(q2, q3, p2) + (V).w; \
    p0 = n0; p1 = n1; p2 = n2; p3 = n3; }

#define GROUP8(Bk) \
    STEP_PQ(Bk##0) STEP_QP(Bk##1) STEP_PQ(Bk##2) STEP_QP(Bk##3) \
    STEP_PQ(Bk##4) STEP_QP(Bk##5) STEP_PQ(Bk##6) STEP_QP(Bk##7)

    float4 A0,A1,A2,A3,A4,A5,A6,A7;
    float4 B0,B1,B2,B3,B4,B5,B6,B7;
    float4 C0,C1,C2,C3,C4,C5,C6,C7;
    float4 E0,E1,E2,E3,E4,E5,E6,E7;
    LOADG(A, 0) LOADG(B, 1) LOADG(C, 2) LOADG(E, 3)
    for (int m = 0; m < 60; m += 4){       // consumes groups 0..59 (s = 1..480)
        GROUP8(A) LOADG(A, m + 4)
        GROUP8(B) LOADG(B, m + 5)
        GROUP8(C) LOADG(C, m + 6)
        GROUP8(E) LOADG(E, m + 7)
    }
    GROUP8(A)                               // group 60: s = 481..488
    GROUP8(B)                               // group 61: s = 489..496
    GROUP8(C)                               // group 62: s = 497..504
    STEP_PQ(E0) STEP_QP(E1) STEP_PQ(E2) STEP_QP(E3) STEP_PQ(E4) STEP_QP(E5) // 505..510

    if (L == 63) out[b] = p3;               // dp[510][255]
#undef LOADG
#undef STEP_PQ
#undef STEP_QP
#undef GROUP8
}

// ---------------- Fallback (tiny ws): fused, D on the fly ----------------
__device__ __forceinline__ float cell_d(const float4* __restrict__ Xb,
                                        const float4* __restrict__ Yb,
                                        int i, int j)
{
    const float4* xr = Xb + i*16;
    const float4* yr = Yb + j*16;
    float acc = 0.f;
    #pragma unroll
    for (int k = 0; k < 16; ++k){
        float4 a = xr[k], bb = yr[k];
        float dx = a.x-bb.x, dy = a.y-bb.y, dz = a.z-bb.z, dw = a.w-bb.w;
        acc += dx*dx + dy*dy + dz*dz + dw*dw;
    }
    return acc;
}

__global__ __launch_bounds__(64) void ldtw_fused_fb(const float* __restrict__ X,
                                                    const float* __restrict__ Y,
                                                    float* __restrict__ out)
{
    const int b = blockIdx.x;
    const int l = threadIdx.x;
    const float4* Xb = (const float4*)(X + (size_t)b * NPT * 64);
    const float4* Yb = (const float4*)(Y + (size_t)b * NPT * 64);
    float prev1 = (l == 0) ? cell_d(Xb, Yb, 0, 0) : BIGV;
    float prev2 = BIGV;
    int base1 = 0, base2 = 0;
    for (int s = 1; s <= 510; ++s){
        const int im = imin_of(s);
        const int ix = imax_of(s);
        const int i  = im + l;
        const bool act = (i <= ix);
        const int ic = act ? i : ix;
        const int j  = s - ic;
        float Dv = cell_d(Xb, Yb, ic, j);
        const int d1 = im - base1, d2 = im - base2;
        float sr1 = dpp_shr1(prev1), sl1 = dpp_shl1(prev1);
        float sr2 = dpp_shr1(prev2), sl2 = dpp_shl1(prev2);
        float m1 = d1 ? fminf(prev1, sl1) : fminf(sr1, prev1);
        float vd = (d2 == 0) ? sr2 : ((d2 == 2) ? sl2 : prev2);
        float m3 = fminf(m1, vd);
        float cur = act ? (m3 + Dv) : BIGV;
        prev2 = prev1; base2 = base1;
        prev1 = cur;   base1 = im;
    }
    if (l == 0) out[b] = prev1;
}

extern "C" void kernel_launch(void* const* d_in, const int* in_sizes, int n_in,
                              void* d_out, int out_size, void* d_ws, size_t ws_size,
                              hipStream_t stream)
{
    const float* X = (const float*)d_in[0];
    const float* Y = (const float*)d_in[1];
    float* out = (float*)d_out;
    const int Bn = in_sizes[0] / (NPT * 64);     // = 16
    // Df: Bn * 512 rows * 256 f32 = Bn * 512 KiB; + slack for group-63 over-read
    const size_t need = (size_t)Bn * 512 * 256 * 4 + 4096;
    if (ws_size >= need){
        float* Df = (float*)d_ws;
        hipLaunchKernelGGL(ldtw_dist, dim3(Bn * 8), dim3(256), 0, stream, X, Y, Df);
        hipLaunchKernelGGL(ldtw_dp,   dim3(Bn),     dim3(64),  0, stream, Df, out);
    } else {
        hipLaunchKernelGGL(ldtw_fused_fb, dim3(Bn), dim3(64), 0, stream, X, Y, out);
    }
}